// Round 1
// baseline (1126.048 us; speedup 1.0000x reference)
//
#include <hip/hip_runtime.h>

// Problem constants (match reference)
#define P_      128
#define NV      512
#define GRID_   112
#define HW_     (GRID_*GRID_)
#define C_      64
#define S_      128
#define IN_DIM_ 66
#define TN      16   // vertices per gconv block

// ---------------------------------------------------------------------------
// Kernel 1: sampling + concat -> inp [P, NV, 66]
// one wave (64 lanes) per vertex; lane = channel (C_=64, coalesced 256B rows)
// ---------------------------------------------------------------------------
__global__ __launch_bounds__(256) void sample_kernel(
    const float* __restrict__ feature,   // [P, HW, C]
    const float* __restrict__ poly,      // [P, NV, 2]
    float* __restrict__ inp,             // [P, NV, IN_DIM]
    int nearest)
{
    int w    = threadIdx.x >> 6;
    int lane = threadIdx.x & 63;
    int g    = blockIdx.x * 4 + w;       // global vertex id
    int p    = g >> 9;                   // NV = 512
    float px = poly[2*g + 0];
    float py = poly[2*g + 1];
    const float* fb = feature + (size_t)p * HW_ * C_;
    float val;
    if (nearest) {
        float X0 = fminf(fmaxf(floorf(px * (float)GRID_), 0.f), (float)(GRID_-1));
        float Y0 = fminf(fmaxf(floorf(py * (float)GRID_), 0.f), (float)(GRID_-1));
        int id = (int)X0 + (int)Y0 * GRID_;
        val = fb[(size_t)id * C_ + lane];
    } else {
        float Xs = px * (float)GRID_, Ys = py * (float)GRID_;
        float X0 = floorf(Xs), Y0 = floorf(Ys);
        float X1 = X0 + 1.f,  Y1 = Y0 + 1.f;
        float ax = X1 - Xs, bx = Xs - X0;
        float ay = Y1 - Ys, by = Ys - Y0;
        int X0c = (int)fminf(fmaxf(X0, 0.f), (float)(GRID_-1));
        int X1c = (int)fminf(fmaxf(X1, 0.f), (float)(GRID_-1));
        int Y0c = (int)fminf(fmaxf(Y0, 0.f), (float)(GRID_-1));
        int Y1c = (int)fminf(fmaxf(Y1, 0.f), (float)(GRID_-1));
        float m00 = fb[(size_t)(X0c + Y0c*GRID_) * C_ + lane];
        float m01 = fb[(size_t)(X0c + Y1c*GRID_) * C_ + lane];
        float m10 = fb[(size_t)(X1c + Y0c*GRID_) * C_ + lane];
        float m11 = fb[(size_t)(X1c + Y1c*GRID_) * C_ + lane];
        val = (ax*ay)*m00 + (ax*by)*m01 + (bx*ay)*m10 + (bx*by)*m11;
    }
    float* row = inp + (size_t)g * IN_DIM_;
    row[lane] = val;
    if (lane == 0) row[64] = px;
    if (lane == 1) row[65] = py;
}

// ---------------------------------------------------------------------------
// Kernel 2: ring graph-conv layer: out = relu(x@Ws + ringavg(x)@Wn + b)
// block = one polygon x TN-vertex tile; halo +-2 rows staged in LDS.
// thread -> 4 vertices x 2 output columns (float2 everywhere).
// ---------------------------------------------------------------------------
template<int D, int RELU>
__global__ __launch_bounds__(256) void gconv_kernel(
    const float* __restrict__ x,     // [P, NV, D]
    const float* __restrict__ Ws,    // [D, S]
    const float* __restrict__ Wn,    // [D, S]
    const float* __restrict__ bias,  // [S]
    float* __restrict__ out)         // [P, NV, S]
{
    __shared__ float xs[TN+4][D];
    __shared__ float nbr[TN][D];
    int p  = blockIdx.x >> 5;            // NV/TN = 32 tiles per polygon
    int n0 = (blockIdx.x & 31) * TN;
    const float* xp = x + (size_t)p * NV * D;

    for (int idx = threadIdx.x; idx < (TN+4)*D; idx += 256) {
        int r = idx / D, c = idx - r*D;
        int n = (n0 - 2 + r) & (NV - 1);
        xs[r][c] = xp[(size_t)n * D + c];
    }
    __syncthreads();
    for (int idx = threadIdx.x; idx < TN*D; idx += 256) {
        int r = idx / D, c = idx - r*D;
        // vertex v=r lives in xs row r+2; neighbors n-2,n-1,n+1,n+2
        nbr[r][c] = 0.25f * (xs[r][c] + xs[r+1][c] + xs[r+3][c] + xs[r+4][c]);
    }
    __syncthreads();

    int s  = (threadIdx.x & 63) * 2;
    int vb = (threadIdx.x >> 6) * 4;
    float acc[4][2];
    #pragma unroll
    for (int j = 0; j < 4; j++) { acc[j][0] = bias[s]; acc[j][1] = bias[s+1]; }

    for (int d = 0; d < D; d += 2) {
        float2 ws0 = *(const float2*)(Ws + (size_t)d*S_ + s);
        float2 ws1 = *(const float2*)(Ws + (size_t)(d+1)*S_ + s);
        float2 wn0 = *(const float2*)(Wn + (size_t)d*S_ + s);
        float2 wn1 = *(const float2*)(Wn + (size_t)(d+1)*S_ + s);
        #pragma unroll
        for (int j = 0; j < 4; j++) {
            float2 xv = *(const float2*)(&xs[vb+j+2][d]);
            float2 nv = *(const float2*)(&nbr[vb+j][d]);
            acc[j][0] += xv.x*ws0.x + xv.y*ws1.x + nv.x*wn0.x + nv.y*wn1.x;
            acc[j][1] += xv.x*ws0.y + xv.y*ws1.y + nv.x*wn0.y + nv.y*wn1.y;
        }
    }

    #pragma unroll
    for (int j = 0; j < 4; j++) {
        float a0 = acc[j][0], a1 = acc[j][1];
        if (RELU) { a0 = fmaxf(a0, 0.f); a1 = fmaxf(a1, 0.f); }
        *(float2*)(out + ((size_t)p*NV + n0 + vb + j)*S_ + s) = make_float2(a0, a1);
    }
}

// ---------------------------------------------------------------------------
// Kernel 3: gconv layer2 (D=128, relu) fused with FC head + poly update.
// h2 tile stays in LDS; threads 0..31 do the 128->2 FC per vertex.
// ---------------------------------------------------------------------------
__global__ __launch_bounds__(256) void g2fc_kernel(
    const float* __restrict__ x,       // h1 [P, NV, S]
    const float* __restrict__ Ws,      // [S, S]
    const float* __restrict__ Wn,      // [S, S]
    const float* __restrict__ bias,    // [S]
    const float* __restrict__ Wfc,     // [S, 2]
    const float* __restrict__ bfc,     // [2]
    const float* __restrict__ poly_in, // [P, NV, 2]
    float* __restrict__ poly_out)      // [P, NV, 2]
{
    constexpr int D = S_;
    __shared__ float xs[TN+4][D];
    __shared__ float nbr[TN][D];
    __shared__ float hs[TN][S_];
    int p  = blockIdx.x >> 5;
    int n0 = (blockIdx.x & 31) * TN;
    const float* xp = x + (size_t)p * NV * D;

    for (int idx = threadIdx.x; idx < (TN+4)*D; idx += 256) {
        int r = idx / D, c = idx - r*D;
        int n = (n0 - 2 + r) & (NV - 1);
        xs[r][c] = xp[(size_t)n * D + c];
    }
    __syncthreads();
    for (int idx = threadIdx.x; idx < TN*D; idx += 256) {
        int r = idx / D, c = idx - r*D;
        nbr[r][c] = 0.25f * (xs[r][c] + xs[r+1][c] + xs[r+3][c] + xs[r+4][c]);
    }
    __syncthreads();

    int s  = (threadIdx.x & 63) * 2;
    int vb = (threadIdx.x >> 6) * 4;
    float acc[4][2];
    #pragma unroll
    for (int j = 0; j < 4; j++) { acc[j][0] = bias[s]; acc[j][1] = bias[s+1]; }

    for (int d = 0; d < D; d += 2) {
        float2 ws0 = *(const float2*)(Ws + (size_t)d*S_ + s);
        float2 ws1 = *(const float2*)(Ws + (size_t)(d+1)*S_ + s);
        float2 wn0 = *(const float2*)(Wn + (size_t)d*S_ + s);
        float2 wn1 = *(const float2*)(Wn + (size_t)(d+1)*S_ + s);
        #pragma unroll
        for (int j = 0; j < 4; j++) {
            float2 xv = *(const float2*)(&xs[vb+j+2][d]);
            float2 nv = *(const float2*)(&nbr[vb+j][d]);
            acc[j][0] += xv.x*ws0.x + xv.y*ws1.x + nv.x*wn0.x + nv.y*wn1.x;
            acc[j][1] += xv.x*ws0.y + xv.y*ws1.y + nv.x*wn0.y + nv.y*wn1.y;
        }
    }

    #pragma unroll
    for (int j = 0; j < 4; j++) {
        float a0 = fmaxf(acc[j][0], 0.f);
        float a1 = fmaxf(acc[j][1], 0.f);
        hs[vb+j][s]   = a0;
        hs[vb+j][s+1] = a1;
    }
    __syncthreads();

    if (threadIdx.x < 32) {
        int v = threadIdx.x >> 1;
        int j = threadIdx.x & 1;
        float pr = bfc[j];
        for (int ss = 0; ss < S_; ss++) pr += hs[v][ss] * Wfc[ss*2 + j];
        size_t o = ((size_t)p*NV + n0 + v) * 2 + j;
        poly_out[o] = poly_in[o] + pr;
    }
}

// ---------------------------------------------------------------------------
extern "C" void kernel_launch(void* const* d_in, const int* in_sizes, int n_in,
                              void* d_out, int out_size, void* d_ws, size_t ws_size,
                              hipStream_t stream)
{
    const float* feature    = (const float*)d_in[0];
    const float* init_polys = (const float*)d_in[1];
    // d_in[2] = adj : ring graph hard-coded (0.25 * (n+-1, n+-2))
    const float* W1s = (const float*)d_in[3];
    const float* W1n = (const float*)d_in[4];
    const float* b1  = (const float*)d_in[5];
    const float* W2s = (const float*)d_in[6];
    const float* W2n = (const float*)d_in[7];
    const float* b2  = (const float*)d_in[8];
    const float* Wfc = (const float*)d_in[9];
    const float* bfc = (const float*)d_in[10];
    float* out = (float*)d_out;

    float* ws    = (float*)d_ws;
    float* polyA = ws;                                  // [P,NV,2]
    float* polyB = polyA + (size_t)P_*NV*2;             // [P,NV,2]
    float* inp   = polyB + (size_t)P_*NV*2;             // [P,NV,66]
    float* h1    = inp   + (size_t)P_*NV*IN_DIM_;       // [P,NV,128]

    hipMemcpyAsync(polyA, init_polys, (size_t)P_*NV*2*sizeof(float),
                   hipMemcpyDeviceToDevice, stream);

    const float* pin = polyA;
    for (int i = 0; i < 3; i++) {
        float* pout = (i == 2) ? out : ((i == 0) ? polyB : polyA);
        sample_kernel<<<P_*NV/4, 256, 0, stream>>>(feature, pin, inp, i == 0);
        gconv_kernel<IN_DIM_, 1><<<P_*(NV/TN), 256, 0, stream>>>(
            inp, W1s + (size_t)i*IN_DIM_*S_, W1n + (size_t)i*IN_DIM_*S_,
            b1 + (size_t)i*S_, h1);
        g2fc_kernel<<<P_*(NV/TN), 256, 0, stream>>>(
            h1, W2s + (size_t)i*S_*S_, W2n + (size_t)i*S_*S_, b2 + (size_t)i*S_,
            Wfc + (size_t)i*S_*2, bfc + (size_t)i*2, pin, pout);
        pin = pout;
    }
}

// Round 2
// 656.052 us; speedup vs baseline: 1.7164x; 1.7164x over previous
//
#include <hip/hip_runtime.h>

// Problem constants (match reference)
#define P_      128
#define NV      512
#define GRID_   112
#define HW_     (GRID_*GRID_)
#define C_      64
#define S_      128
#define IN_DIM_ 66

typedef short bf16x8 __attribute__((ext_vector_type(8)));
typedef float f32x4  __attribute__((ext_vector_type(4)));

__device__ __forceinline__ unsigned short f2bf(float x) {
    union { float f; unsigned int u; } v; v.f = x;
    unsigned int r = (v.u + 0x7FFFu + ((v.u >> 16) & 1u)) >> 16;
    return (unsigned short)r;
}
__device__ __forceinline__ float2 up2(unsigned int u) {
    union { unsigned int u; float f; } a, b;
    a.u = u << 16; b.u = u & 0xFFFF0000u;
    return make_float2(a.f, b.f);
}
__device__ __forceinline__ unsigned int pk2(float lo, float hi) {
    return (unsigned int)f2bf(lo) | ((unsigned int)f2bf(hi) << 16);
}

// ---------------------------------------------------------------------------
// One-time weight packer: [Ws;Wn] combined, zero-padded K, B-fragment order
// for mfma_f32_16x16x32_bf16: B[k = ks*32 + (lane>>4)*8 + j][n = nt*16 + (lane&15)]
// packed[( (step*KS + ks)*8 + nt )*64 + lane][j]
// ---------------------------------------------------------------------------
__global__ __launch_bounds__(256) void wprep_kernel(
    const float* __restrict__ W1s, const float* __restrict__ W1n,
    const float* __restrict__ W2s, const float* __restrict__ W2n,
    unsigned short* __restrict__ W1p, unsigned short* __restrict__ W2p)
{
    int idx = blockIdx.x * 256 + threadIdx.x;
    const int N1 = 3 * 5 * 8 * 64 * 8;   // 61440  (K=160)
    const int N2 = 3 * 8 * 8 * 64 * 8;   // 98304  (K=256)
    if (idx < N1) {
        int j = idx & 7, lane = (idx >> 3) & 63, nt = (idx >> 9) & 7;
        int ks = (idx >> 12) % 5, step = idx / 20480;
        int n = nt * 16 + (lane & 15);
        int k = ks * 32 + (lane >> 4) * 8 + j;
        float v = 0.f;
        if (k < 66)       v = W1s[(step * 66 + k) * 128 + n];
        else if (k < 132) v = W1n[(step * 66 + (k - 66)) * 128 + n];
        W1p[idx] = f2bf(v);
    } else if (idx < N1 + N2) {
        int e = idx - N1;
        int j = e & 7, lane = (e >> 3) & 63, nt = (e >> 9) & 7;
        int ks = (e >> 12) & 7, step = e >> 15;
        int n = nt * 16 + (lane & 15);
        int k = ks * 32 + (lane >> 4) * 8 + j;
        float v = (k < 128) ? W2s[(step * 128 + k) * 128 + n]
                            : W2n[(step * 128 + (k - 128)) * 128 + n];
        W2p[e] = f2bf(v);
    }
}

// ---------------------------------------------------------------------------
// Sampling + concat -> inp [P*NV][72] bf16 (cols 0..63 feat, 64..65 poly, rest 0)
// one wave per vertex; lane = channel
// ---------------------------------------------------------------------------
__global__ __launch_bounds__(256) void sample_kernel(
    const float* __restrict__ feature, const float* __restrict__ poly,
    unsigned short* __restrict__ inp, int nearest)
{
    int w = threadIdx.x >> 6, lane = threadIdx.x & 63;
    int g = blockIdx.x * 4 + w;
    int p = g >> 9;
    float px = poly[2 * g], py = poly[2 * g + 1];
    const float* fb = feature + (size_t)p * HW_ * C_;
    float val;
    if (nearest) {
        float X0 = fminf(fmaxf(floorf(px * (float)GRID_), 0.f), (float)(GRID_ - 1));
        float Y0 = fminf(fmaxf(floorf(py * (float)GRID_), 0.f), (float)(GRID_ - 1));
        int id = (int)X0 + (int)Y0 * GRID_;
        val = fb[(size_t)id * C_ + lane];
    } else {
        float Xs = px * (float)GRID_, Ys = py * (float)GRID_;
        float X0 = floorf(Xs), Y0 = floorf(Ys);
        float X1 = X0 + 1.f, Y1 = Y0 + 1.f;
        float ax = X1 - Xs, bx = Xs - X0;
        float ay = Y1 - Ys, by = Ys - Y0;
        int X0c = (int)fminf(fmaxf(X0, 0.f), (float)(GRID_ - 1));
        int X1c = (int)fminf(fmaxf(X1, 0.f), (float)(GRID_ - 1));
        int Y0c = (int)fminf(fmaxf(Y0, 0.f), (float)(GRID_ - 1));
        int Y1c = (int)fminf(fmaxf(Y1, 0.f), (float)(GRID_ - 1));
        float m00 = fb[(size_t)(X0c + Y0c * GRID_) * C_ + lane];
        float m01 = fb[(size_t)(X0c + Y1c * GRID_) * C_ + lane];
        float m10 = fb[(size_t)(X1c + Y0c * GRID_) * C_ + lane];
        float m11 = fb[(size_t)(X1c + Y1c * GRID_) * C_ + lane];
        val = (ax * ay) * m00 + (ax * by) * m01 + (bx * ay) * m10 + (bx * by) * m11;
    }
    unsigned short* row = inp + (size_t)g * 72;
    row[lane] = f2bf(val);
    if (lane < 8) {
        float v2 = (lane == 0) ? px : (lane == 1) ? py : 0.f;
        row[64 + lane] = f2bf(v2);
    }
}

// ---------------------------------------------------------------------------
// Layer 1: h1 = relu([x|nbr] @ W1packed + b1), M=64/block, K=160(pad), N=128
// ---------------------------------------------------------------------------
__global__ __launch_bounds__(256) void gemm1_kernel(
    const unsigned short* __restrict__ inp,  // [P*NV][72] bf16
    const unsigned short* __restrict__ W1p,  // step offset applied
    const float* __restrict__ b1,
    unsigned short* __restrict__ h1)         // [P*NV][128] bf16
{
    __shared__ __align__(16) unsigned int As[64 * 84];  // [64 rows][pitch 168 bf16]
    int p = blockIdx.x >> 3, n0 = (blockIdx.x & 7) * 64;
    const unsigned int* inpu = (const unsigned int*)(inp + (size_t)p * NV * 72);

    for (int idx = threadIdx.x; idx < 64 * 84; idx += 256) {
        int r = idx / 84, u = idx - r * 84;
        unsigned int val;
        if (u < 33) {                       // x part: cols 0..65
            val = inpu[(n0 + r) * 36 + u];
        } else if (u < 66) {                // nbr part: cols 66..131
            int uu = u - 33;
            unsigned int a = inpu[((n0 + r - 2) & 511) * 36 + uu];
            unsigned int b = inpu[((n0 + r - 1) & 511) * 36 + uu];
            unsigned int c = inpu[((n0 + r + 1) & 511) * 36 + uu];
            unsigned int d = inpu[((n0 + r + 2) & 511) * 36 + uu];
            float2 fa = up2(a), fb = up2(b), fc = up2(c), fd = up2(d);
            val = pk2(0.25f * (fa.x + fb.x + fc.x + fd.x),
                      0.25f * (fa.y + fb.y + fc.y + fd.y));
        } else val = 0u;                    // zero pad cols 132..167
        As[idx] = val;
    }
    __syncthreads();

    int wv = threadIdx.x >> 6, lane = threadIdx.x & 63;
    int m = lane & 15, q = lane >> 4;
    const unsigned short* Asrow = (const unsigned short*)As + (wv * 16 + m) * 168 + q * 8;
    f32x4 acc[8];
    #pragma unroll
    for (int nt = 0; nt < 8; nt++) acc[nt] = (f32x4){0.f, 0.f, 0.f, 0.f};
    const bf16x8* Bp = (const bf16x8*)W1p;
    for (int ks = 0; ks < 5; ks++) {
        bf16x8 a = *(const bf16x8*)(Asrow + ks * 32);
        #pragma unroll
        for (int nt = 0; nt < 8; nt++) {
            bf16x8 b = Bp[(ks * 8 + nt) * 64 + lane];
            acc[nt] = __builtin_amdgcn_mfma_f32_16x16x32_bf16(a, b, acc[nt], 0, 0, 0);
        }
    }
    unsigned short* h1b = h1 + ((size_t)p * NV + n0) * 128;
    #pragma unroll
    for (int nt = 0; nt < 8; nt++) {
        int col = nt * 16 + m;
        float bias = b1[col];
        #pragma unroll
        for (int rg = 0; rg < 4; rg++) {
            int row = wv * 16 + q * 4 + rg;
            h1b[row * 128 + col] = f2bf(fmaxf(acc[nt][rg] + bias, 0.f));
        }
    }
}

// ---------------------------------------------------------------------------
// Layer 2 + FC + poly update: h2 = relu([h1|nbr] @ W2packed + b2) (K=256),
// pred = h2 @ Wfc + bfc, poly_out = poly_in + pred. h2 stays in LDS.
// ---------------------------------------------------------------------------
__global__ __launch_bounds__(256) void gemm2fc_kernel(
    const unsigned short* __restrict__ h1,   // [P*NV][128] bf16
    const unsigned short* __restrict__ W2p,
    const float* __restrict__ b2,
    const float* __restrict__ Wfc, const float* __restrict__ bfc,
    const float* __restrict__ poly_in, float* __restrict__ poly_out)
{
    __shared__ __align__(16) char smem[64 * 132 * 4 + 68 * 64 * 4]; // 51.2 KB
    unsigned int* As2 = (unsigned int*)smem;                // [64][132] (pitch 264 bf16)
    unsigned int* raw = (unsigned int*)(smem + 64 * 132 * 4); // [68][64]
    float* h2 = (float*)smem;                               // [64][129] aliases As2

    int p = blockIdx.x >> 3, n0 = (blockIdx.x & 7) * 64;
    const unsigned int* h1u = (const unsigned int*)h1 + (size_t)p * NV * 64;

    for (int idx = threadIdx.x; idx < 68 * 64; idx += 256) {
        int r = idx >> 6, u = idx & 63;
        raw[idx] = h1u[(size_t)((n0 + r - 2) & 511) * 64 + u];
    }
    __syncthreads();
    for (int idx = threadIdx.x; idx < 64 * 132; idx += 256) {
        int r = idx / 132, u = idx - r * 132;
        unsigned int val;
        if (u < 64) val = raw[(r + 2) * 64 + u];
        else if (u < 128) {
            int uu = u - 64;
            float2 fa = up2(raw[r * 64 + uu]),       fb = up2(raw[(r + 1) * 64 + uu]);
            float2 fc = up2(raw[(r + 3) * 64 + uu]), fd = up2(raw[(r + 4) * 64 + uu]);
            val = pk2(0.25f * (fa.x + fb.x + fc.x + fd.x),
                      0.25f * (fa.y + fb.y + fc.y + fd.y));
        } else val = 0u;
        As2[idx] = val;
    }
    __syncthreads();

    int wv = threadIdx.x >> 6, lane = threadIdx.x & 63;
    int m = lane & 15, q = lane >> 4;
    const unsigned short* Asrow = (const unsigned short*)As2 + (wv * 16 + m) * 264 + q * 8;
    f32x4 acc[8];
    #pragma unroll
    for (int nt = 0; nt < 8; nt++) acc[nt] = (f32x4){0.f, 0.f, 0.f, 0.f};
    const bf16x8* Bp = (const bf16x8*)W2p;
    for (int ks = 0; ks < 8; ks++) {
        bf16x8 a = *(const bf16x8*)(Asrow + ks * 32);
        #pragma unroll
        for (int nt = 0; nt < 8; nt++) {
            bf16x8 b = Bp[(ks * 8 + nt) * 64 + lane];
            acc[nt] = __builtin_amdgcn_mfma_f32_16x16x32_bf16(a, b, acc[nt], 0, 0, 0);
        }
    }
    __syncthreads();   // all waves done reading As2 before aliasing with h2
    #pragma unroll
    for (int nt = 0; nt < 8; nt++) {
        int col = nt * 16 + m;
        float bias = b2[col];
        #pragma unroll
        for (int rg = 0; rg < 4; rg++) {
            int row = wv * 16 + q * 4 + rg;
            h2[row * 129 + col] = fmaxf(acc[nt][rg] + bias, 0.f);
        }
    }
    __syncthreads();
    if (threadIdx.x < 128) {
        int v = threadIdx.x >> 1, j = threadIdx.x & 1;
        float pr = bfc[j];
        const float* hv = h2 + v * 129;
        for (int c = 0; c < 128; c++) pr += hv[c] * Wfc[c * 2 + j];
        size_t o = ((size_t)p * NV + n0 + v) * 2 + j;
        poly_out[o] = poly_in[o] + pr;
    }
}

// ---------------------------------------------------------------------------
extern "C" void kernel_launch(void* const* d_in, const int* in_sizes, int n_in,
                              void* d_out, int out_size, void* d_ws, size_t ws_size,
                              hipStream_t stream)
{
    const float* feature    = (const float*)d_in[0];
    const float* init_polys = (const float*)d_in[1];
    // d_in[2] = adj : ring graph hard-coded (0.25 * (n+-1, n+-2))
    const float* W1s = (const float*)d_in[3];
    const float* W1n = (const float*)d_in[4];
    const float* b1  = (const float*)d_in[5];
    const float* W2s = (const float*)d_in[6];
    const float* W2n = (const float*)d_in[7];
    const float* b2  = (const float*)d_in[8];
    const float* Wfc = (const float*)d_in[9];
    const float* bfc = (const float*)d_in[10];
    float* out = (float*)d_out;

    char* wsb = (char*)d_ws;
    float* polyA = (float*)wsb;                  wsb += (size_t)131072 * 4;
    float* polyB = (float*)wsb;                  wsb += (size_t)131072 * 4;
    unsigned short* W1p = (unsigned short*)wsb;  wsb += (size_t)61440 * 2;
    unsigned short* W2p = (unsigned short*)wsb;  wsb += (size_t)98304 * 2;
    unsigned short* inp = (unsigned short*)wsb;  wsb += (size_t)P_ * NV * 72 * 2;
    unsigned short* h1  = (unsigned short*)wsb;  wsb += (size_t)P_ * NV * 128 * 2;

    wprep_kernel<<<624, 256, 0, stream>>>(W1s, W1n, W2s, W2n, W1p, W2p);

    const float* pin = init_polys;
    for (int i = 0; i < 3; i++) {
        float* pout = (i == 2) ? out : ((i == 0) ? polyA : polyB);
        sample_kernel<<<P_ * NV / 4, 256, 0, stream>>>(feature, pin, inp, i == 0);
        gemm1_kernel<<<P_ * 8, 256, 0, stream>>>(
            inp, W1p + (size_t)i * 20480, b1 + i * 128, h1);
        gemm2fc_kernel<<<P_ * 8, 256, 0, stream>>>(
            h1, W2p + (size_t)i * 32768, b2 + i * 128,
            Wfc + i * 256, bfc + i * 2, pin, pout);
        pin = pout;
    }
}